// Round 6
// baseline (960.659 us; speedup 1.0000x reference)
//
#include <hip/hip_runtime.h>
#include <cmath>

#define BB 32
#define TT 4096

typedef unsigned short u16;
typedef __attribute__((ext_vector_type(8))) __bf16 bf16x8;
typedef __attribute__((ext_vector_type(4))) float f32x4;
typedef __attribute__((ext_vector_type(8))) unsigned short u16x8;
typedef __attribute__((ext_vector_type(4))) unsigned short u16x4;
typedef __attribute__((ext_vector_type(2))) unsigned short u16x2;
typedef __attribute__((ext_vector_type(4))) unsigned int u32x4;

typedef __attribute__((address_space(3))) unsigned int lds_uint;
typedef __attribute__((address_space(1))) unsigned int g_uint;

__device__ __forceinline__ void gl_lds16(const void* g, void* l) {
    __builtin_amdgcn_global_load_lds((const g_uint*)g, (lds_uint*)l, 16, 0, 0);
}

__device__ __forceinline__ u16 f2b(float x) {
    unsigned u = __builtin_bit_cast(unsigned, x);
    return (u16)((u + 0x7fffu + ((u >> 16) & 1u)) >> 16);
}
__device__ __forceinline__ float b2f(u16 h) {
    unsigned u = ((unsigned)h) << 16;
    return __builtin_bit_cast(float, u);
}
__device__ __forceinline__ unsigned pkbf(float a, float b) {
    unsigned ua = __builtin_bit_cast(unsigned, a) + 0x8000u;
    unsigned ub = __builtin_bit_cast(unsigned, b) + 0x8000u;
    return __builtin_amdgcn_perm(ub, ua, 0x07060302);
}

// ---- bf16 weight area offsets (elements) ----
enum : int {
  W_TB0_1 = 0,
  W_TB0_2 = 32768,
  W_TB0_D = 98304,
  W_TB1_1_T0 = 131072, W_TB1_1_T1 = 196608,
  W_TB1_2_T0 = 262144, W_TB1_2_T1 = 327680,
  W_TB2_1_T0 = 393216, W_TB2_1_T1 = 458752,
  W_TB2_2_T0 = 524288, W_TB2_2_T1 = 589824,
  W_TB3_1_T0 = 655360, W_TB3_1_T1 = 720896,
  W_TB3_2_T0 = 786432, W_TB3_2_T1 = 851968,
  W_ATTN_IN  = 917504,
  W_ATTN_OUT = 1114112,
  W_FFN1     = 1179648,
  W_FFN2     = 1310720,
};

__global__ __launch_bounds__(256)
void prep_weights(const float* s0, const float* s1, const float* s2,
                  const float* s3, const float* s4, const float* s5,
                  const float* s6, const float* s7, const float* s8,
                  const float* s9, const float* s10, const float* s11,
                  const float* s12, u16* wb)
{
    int seg = blockIdx.y;
    int i = blockIdx.x * 256 + threadIdx.x;
    switch (seg) {
    case 0:  if (i < 32768)  wb[W_TB0_1 + i] = f2b(s0[i]); break;
    case 1:  if (i < 65536)  wb[W_TB0_2 + i] = f2b(s1[i]); break;
    case 2:  if (i < 32768)  wb[W_TB0_D + i] = f2b(s2[i]); break;
    case 3:  if (i < 65536) { wb[W_TB1_1_T0 + i] = f2b(s3[2*i]); wb[W_TB1_1_T1 + i] = f2b(s3[2*i+1]); } break;
    case 4:  if (i < 65536) { wb[W_TB1_2_T0 + i] = f2b(s4[2*i]); wb[W_TB1_2_T1 + i] = f2b(s4[2*i+1]); } break;
    case 5:  if (i < 65536) { wb[W_TB2_1_T0 + i] = f2b(s5[2*i]); wb[W_TB2_1_T1 + i] = f2b(s5[2*i+1]); } break;
    case 6:  if (i < 65536) { wb[W_TB2_2_T0 + i] = f2b(s6[2*i]); wb[W_TB2_2_T1 + i] = f2b(s6[2*i+1]); } break;
    case 7:  if (i < 65536) { wb[W_TB3_1_T0 + i] = f2b(s7[2*i]); wb[W_TB3_1_T1 + i] = f2b(s7[2*i+1]); } break;
    case 8:  if (i < 65536) { wb[W_TB3_2_T0 + i] = f2b(s8[2*i]); wb[W_TB3_2_T1 + i] = f2b(s8[2*i+1]); } break;
    case 9:  if (i < 196608) wb[W_ATTN_IN + i]  = f2b(s9[i]);  break;
    case 10: if (i < 65536)  wb[W_ATTN_OUT + i] = f2b(s10[i]); break;
    case 11: if (i < 131072) wb[W_FFN1 + i]     = f2b(s11[i]); break;
    case 12: if (i < 131072) wb[W_FFN2 + i]     = f2b(s12[i]); break;
    }
}

// z [Bc,128,T] fp32 -> Z [Bc,T,128] bf16 (token-major)
__global__ __launch_bounds__(256)
void transpose_z(const float* __restrict__ z, u16* __restrict__ Z)
{
    __shared__ u16 tile[64][33];
    const int t0 = blockIdx.x << 6;
    const int c0 = blockIdx.y << 5;
    const int b  = blockIdx.z;
    const int tid = threadIdx.x;
    #pragma unroll
    for (int r = 0; r < 8; r++) {
        int lin = r * 256 + tid;
        int cc = lin >> 6, tt = lin & 63;
        tile[tt][cc] = f2b(z[((size_t)b * 128 + c0 + cc) * TT + t0 + tt]);
    }
    __syncthreads();
    #pragma unroll
    for (int r = 0; r < 8; r++) {
        int lin = r * 256 + tid;
        int tt = lin >> 5, cc = lin & 31;
        Z[((size_t)b * TT + t0 + tt) * 128 + c0 + cc] = tile[tt][cc];
    }
}

// Swizzled LDS fragment address: rows of 128B (8 chunks of 16B); physical chunk = logical ^ (row&7)
__device__ __forceinline__ const bf16x8* lds_frag(const u16* base, int row, int lc) {
    return (const bf16x8*)((const char*)base + row * 128 + (((lc ^ row) & 7) << 4) + ((lc & ~7) << 4));
}

// ===================== 512-thread full-width GEMM =====================
// Block tile: 128 tokens x 256 channels (8 waves, each 64x64).
//   Y[b,t,n0+m] = epi( sum_k X[b,t,k]*W[n0+m,k] + bias[n0+m] )
// ACT (EPI==0 only): 0 none, 1 relu, 2 gelu.  RMODE==1: v = act(acc + res).
// EPI: 0 = plain store bf16;  1 = LN(acc + res) -> store bf16 (xn);
//      2 = LN(acc + res) -> dot(lw) + lb -> out fp32 (no Y store).
template<int ACT, int RMODE, int EPI>
__global__ __launch_bounds__(512)
void gemm512(const u16* __restrict__ X, const u16* __restrict__ W, int K, int M,
             const float* __restrict__ bias,
             const u16* __restrict__ res, u16* __restrict__ Y,
             const float* __restrict__ g, const float* __restrict__ be,
             const float* __restrict__ lw, const float* __restrict__ lb,
             float* __restrict__ out)
{
    __shared__ __align__(16) char smem[49152];     // Xs 16KB + Ws 32KB; CT(33280B) overlays
    u16* Xs = (u16*)smem;
    u16* Ws = (u16*)(smem + 16384);
    float (*CT)[260] = (float(*)[260])smem;

    const int tid = threadIdx.x;
    const int b  = blockIdx.z;
    const int t0 = blockIdx.x << 7;
    const int n0 = blockIdx.y << 8;
    const int lane = tid & 63;
    const int wv = tid >> 6;
    const int wt = (wv >> 2) << 6;      // wave token-offset: 0 or 64
    const int wn = (wv & 3) << 6;       // wave channel-offset: 0..192
    const int l15 = lane & 15;
    const int quad = lane >> 4;

    // staging descriptors
    const char* xsrc[2]; char* xdst[2];
    #pragma unroll
    for (int u = 0; u < 2; u++) {
        const int c = tid + (u << 9);
        const int r = c >> 3, q = (c & 7) ^ (r & 7);
        xdst[u] = (char*)Xs + c * 16;
        xsrc[u] = (const char*)(X + ((size_t)b * TT + t0 + r) * K + q * 8);
    }
    const char* wsrc[4]; char* wdst[4];
    #pragma unroll
    for (int u = 0; u < 4; u++) {
        const int c = tid + (u << 9);
        const int r = c >> 3, q = (c & 7) ^ (r & 7);
        wdst[u] = (char*)Ws + c * 16;
        wsrc[u] = (const char*)(W + (size_t)(n0 + r) * K + q * 8);
    }

    f32x4 acc[4][4];
    #pragma unroll
    for (int j = 0; j < 4; j++) {
        const f32x4 bj = *(const f32x4*)&bias[n0 + wn + j * 16 + quad * 4];
        #pragma unroll
        for (int i = 0; i < 4; i++) acc[i][j] = bj;
    }

    for (int k0 = 0; k0 < K; k0 += 64) {
        #pragma unroll
        for (int u = 0; u < 2; u++) gl_lds16(xsrc[u] + 2 * k0, xdst[u]);
        #pragma unroll
        for (int u = 0; u < 4; u++) gl_lds16(wsrc[u] + 2 * k0, wdst[u]);
        __syncthreads();
        #pragma unroll
        for (int ks = 0; ks < 2; ks++) {
            const int lc = ks * 4 + quad;
            bf16x8 af[4], bw[4];
            #pragma unroll
            for (int i = 0; i < 4; i++)
                af[i] = *lds_frag(Xs, wt + i * 16 + l15, lc);
            #pragma unroll
            for (int j = 0; j < 4; j++)
                bw[j] = *lds_frag(Ws, wn + j * 16 + l15, lc);
            #pragma unroll
            for (int i = 0; i < 4; i++)
                #pragma unroll
                for (int j = 0; j < 4; j++)
                    acc[i][j] = __builtin_amdgcn_mfma_f32_16x16x32_bf16(bw[j], af[i], acc[i][j], 0, 0, 0);
        }
        __syncthreads();
    }

    // ---- epilogue: 4 phases of 32 tokens through CT ----
    const int hsel = wv >> 2;
    #pragma unroll
    for (int h = 0; h < 4; h++) {
        if ((h >> 1) == hsel) {
            const int ibase = (h & 1) * 2;
            #pragma unroll
            for (int i2 = 0; i2 < 2; i2++) {
                const int tt = i2 * 16 + l15;
                #pragma unroll
                for (int j = 0; j < 4; j++)
                    *(f32x4*)&CT[tt][wn + j * 16 + quad * 4] = acc[ibase + i2][j];
            }
        }
        __syncthreads();
        #pragma unroll
        for (int r2 = 0; r2 < 2; r2++) {
            const int lin = (r2 << 9) + tid;
            const int tt = lin >> 5;           // 0..31
            const int ck = lin & 31;           // 8-ch chunk
            const int token = t0 + h * 32 + tt;
            const int gc = n0 + ck * 8;
            f32x4 v0 = *(const f32x4*)&CT[tt][ck * 8];
            f32x4 v1 = *(const f32x4*)&CT[tt][ck * 8 + 4];
            if (RMODE == 1 || EPI >= 1) {
                const u16x8 rv = *(const u16x8*)&res[((size_t)b * TT + token) * 256 + ck * 8];
                #pragma unroll
                for (int e = 0; e < 4; e++) { v0[e] += b2f(rv[e]); v1[e] += b2f(rv[e + 4]); }
            }
            if (EPI == 0) {
                if (ACT == 1) {
                    #pragma unroll
                    for (int e = 0; e < 4; e++) { v0[e] = fmaxf(v0[e], 0.f); v1[e] = fmaxf(v1[e], 0.f); }
                }
                if (ACT == 2) {
                    #pragma unroll
                    for (int e = 0; e < 4; e++) {
                        v0[e] = 0.5f * v0[e] * (1.f + erff(v0[e] * 0.70710678118f));
                        v1[e] = 0.5f * v1[e] * (1.f + erff(v1[e] * 0.70710678118f));
                    }
                }
                u32x4 po;
                po[0] = pkbf(v0[0], v0[1]); po[1] = pkbf(v0[2], v0[3]);
                po[2] = pkbf(v1[0], v1[1]); po[3] = pkbf(v1[2], v1[3]);
                *(u32x4*)&Y[((size_t)b * TT + token) * M + gc] = po;
            } else {
                // LayerNorm over 256 channels: 32-thread group per token
                float s = 0.f, sq = 0.f;
                #pragma unroll
                for (int e = 0; e < 4; e++) {
                    s += v0[e] + v1[e];
                    sq += v0[e] * v0[e] + v1[e] * v1[e];
                }
                #pragma unroll
                for (int off = 16; off >= 1; off >>= 1) {
                    s += __shfl_xor(s, off, 64);
                    sq += __shfl_xor(sq, off, 64);
                }
                const float mean = s * (1.f / 256.f);
                const float var = sq * (1.f / 256.f) - mean * mean;
                const float rstd = rsqrtf(var + 1e-5f);
                const f32x4 g0 = *(const f32x4*)&g[gc];
                const f32x4 g1 = *(const f32x4*)&g[gc + 4];
                const f32x4 be0 = *(const f32x4*)&be[gc];
                const f32x4 be1 = *(const f32x4*)&be[gc + 4];
                f32x4 x0, x1;
                #pragma unroll
                for (int e = 0; e < 4; e++) {
                    x0[e] = (v0[e] - mean) * rstd * g0[e] + be0[e];
                    x1[e] = (v1[e] - mean) * rstd * g1[e] + be1[e];
                }
                if (EPI == 1) {
                    u32x4 po;
                    po[0] = pkbf(x0[0], x0[1]); po[1] = pkbf(x0[2], x0[3]);
                    po[2] = pkbf(x1[0], x1[1]); po[3] = pkbf(x1[2], x1[3]);
                    *(u32x4*)&Y[((size_t)b * TT + token) * 256 + gc] = po;
                } else {
                    const f32x4 w0 = *(const f32x4*)&lw[gc];
                    const f32x4 w1 = *(const f32x4*)&lw[gc + 4];
                    float a = 0.f;
                    #pragma unroll
                    for (int e = 0; e < 4; e++) a += x0[e] * w0[e] + x1[e] * w1[e];
                    #pragma unroll
                    for (int off = 16; off >= 1; off >>= 1) a += __shfl_xor(a, off, 64);
                    if ((lane & 31) == 0) out[(size_t)b * TT + token] = a + lb[0];
                }
            }
        }
        __syncthreads();
    }
}

// ===================== dual-tap conv GEMM (unchanged from R5) =====================
template<int RMODE>
__global__ __launch_bounds__(256)
void gemm_dual(const u16* __restrict__ X, const u16* __restrict__ W1, int K,
               const u16* __restrict__ W2, int sh,
               const float* __restrict__ bias1,
               const u16* __restrict__ res, u16* __restrict__ Y,
               const u16* __restrict__ zp)
{
    constexpr int XR = 132;
    constexpr int STB = (XR + 256) * 128;
    constexpr int SMB = STB > 33792 ? STB : 33792;
    __shared__ __align__(16) char smem[SMB];
    u16* Xs = (u16*)smem;
    u16* Ws = (u16*)(smem + XR * 128);
    float (*CT)[132] = (float(*)[132])smem;

    const int tid = threadIdx.x;
    const int b  = blockIdx.z;
    const int t0 = blockIdx.x << 7;
    const int n0 = blockIdx.y << 7;
    const int lane = tid & 63;
    const int wv = tid >> 6;
    const int wt = (wv >> 1) << 6;
    const int wn = (wv & 1) << 6;
    const int l15 = lane & 15;
    const int quad = lane >> 4;
    const int shl = sh;

    const char* xsrc[4]; char* xdst[4];
    #pragma unroll
    for (int u = 0; u < 4; u++) {
        const int c = tid + (u << 8);
        const int r = c >> 3, p = c & 7, q = p ^ (r & 7);
        const int st = t0 + r - shl;
        xdst[u] = (char*)Xs + c * 16;
        xsrc[u] = (const char*)((st >= 0 ? (X + ((size_t)b * TT + st) * K) : zp) + q * 8);
    }
    const char* wsrc[8]; char* wdst[8];
    #pragma unroll
    for (int u = 0; u < 8; u++) {
        const int c = tid + (u << 8);
        const int r = c >> 3, p = c & 7, q = p ^ (r & 7);
        wdst[u] = (char*)Ws + c * 16;
        const u16* wb_ = (r >= 128) ? (W2 + (size_t)(n0 + r - 128) * K)
                                    : (W1 + (size_t)(n0 + r) * K);
        wsrc[u] = (const char*)(wb_ + q * 8);
    }
    const u16* hsrc = nullptr; u16* hdst = nullptr;
    if (tid < 8 * shl) {
        const int hr = 128 + (tid >> 3), hp = tid & 7, hq = hp ^ (hr & 7);
        hsrc = X + ((size_t)b * TT + t0 + hr - shl) * K + hq * 8;
        hdst = (u16*)((char*)Xs + (1024 + tid) * 16);
    }

    f32x4 acc[4][4];
    #pragma unroll
    for (int j = 0; j < 4; j++) {
        const f32x4 bj = *(const f32x4*)&bias1[n0 + wn + j * 16 + quad * 4];
        #pragma unroll
        for (int i = 0; i < 4; i++) acc[i][j] = bj;
    }

    for (int k0 = 0; k0 < K; k0 += 64) {
        #pragma unroll
        for (int u = 0; u < 4; u++) gl_lds16(xsrc[u] + 2 * k0, xdst[u]);
        #pragma unroll
        for (int u = 0; u < 8; u++) gl_lds16(wsrc[u] + 2 * k0, wdst[u]);
        if (hdst) *(u16x8*)hdst = *(const u16x8*)(hsrc + k0);
        __syncthreads();
        #pragma unroll
        for (int ks = 0; ks < 2; ks++) {
            bf16x8 af[4], bw[4];
            const int lc = ks * 4 + quad;
            #pragma unroll
            for (int i = 0; i < 4; i++)
                af[i] = *lds_frag(Xs, shl + wt + i * 16 + l15, lc);
            #pragma unroll
            for (int j = 0; j < 4; j++)
                bw[j] = *lds_frag(Ws, wn + j * 16 + l15, lc);
            #pragma unroll
            for (int i = 0; i < 4; i++)
                #pragma unroll
                for (int j = 0; j < 4; j++)
                    acc[i][j] = __builtin_amdgcn_mfma_f32_16x16x32_bf16(bw[j], af[i], acc[i][j], 0, 0, 0);
            #pragma unroll
            for (int i = 0; i < 4; i++)
                af[i] = *lds_frag(Xs, wt + i * 16 + l15, lc);
            #pragma unroll
            for (int j = 0; j < 4; j++)
                bw[j] = *lds_frag(Ws, 128 + wn + j * 16 + l15, lc);
            #pragma unroll
            for (int i = 0; i < 4; i++)
                #pragma unroll
                for (int j = 0; j < 4; j++)
                    acc[i][j] = __builtin_amdgcn_mfma_f32_16x16x32_bf16(bw[j], af[i], acc[i][j], 0, 0, 0);
        }
        __syncthreads();
    }

    #pragma unroll
    for (int h = 0; h < 2; h++) {
        if (wt == h * 64) {
            #pragma unroll
            for (int i = 0; i < 4; i++) {
                const int tt = i * 16 + l15;
                #pragma unroll
                for (int j = 0; j < 4; j++)
                    *(f32x4*)&CT[tt][wn + j * 16 + quad * 4] = acc[i][j];
            }
        }
        __syncthreads();
        #pragma unroll
        for (int r4 = 0; r4 < 4; r4++) {
            const int lin = (r4 << 8) + tid;
            const int tt = lin >> 4;
            const int ck = lin & 15;
            const int gr = t0 + h * 64 + tt;
            const int gc = n0 + ck * 8;
            const size_t oidx = ((size_t)b * TT + gr) * 256 + gc;
            f32x4 v0 = *(const f32x4*)&CT[tt][ck * 8];
            f32x4 v1 = *(const f32x4*)&CT[tt][ck * 8 + 4];
            if (RMODE == 2) {
                const u16x8 rv = *(const u16x8*)&res[oidx];
                #pragma unroll
                for (int e = 0; e < 4; e++) {
                    v0[e] = fmaxf(fmaxf(v0[e], 0.f) + b2f(rv[e]), 0.f);
                    v1[e] = fmaxf(fmaxf(v1[e], 0.f) + b2f(rv[e + 4]), 0.f);
                }
            } else {
                #pragma unroll
                for (int e = 0; e < 4; e++) { v0[e] = fmaxf(v0[e], 0.f); v1[e] = fmaxf(v1[e], 0.f); }
            }
            u32x4 po;
            po[0] = pkbf(v0[0], v0[1]); po[1] = pkbf(v0[2], v0[3]);
            po[2] = pkbf(v1[0], v1[1]); po[3] = pkbf(v1[2], v1[3]);
            *(u32x4*)&Y[oidx] = po;
        }
        if (h == 0) __syncthreads();
    }
}

// Sliding-window causal attention, window 8, one block per (p, h, b), one query per thread.
__global__ __launch_bounds__(256)
void attn_win(const u16* __restrict__ QKV, u16* __restrict__ O)
{
    __shared__ u16 KV[256 * 68];
    const int p = blockIdx.x, h = blockIdx.y, b = blockIdx.z;
    const int tid = threadIdx.x;
    const int s = tid;

    float qv[64];
    {
        size_t qg = ((size_t)b * TT + s * 16 + p) * 768 + h * 64;
        #pragma unroll
        for (int c = 0; c < 8; c++) {
            u16x8 u = *(const u16x8*)&QKV[qg + c * 8];
            #pragma unroll
            for (int j = 0; j < 8; j++) qv[c * 8 + j] = b2f(u[j]);
        }
    }
    for (int u = tid; u < 2048; u += 256) {
        int r = u >> 3, q = u & 7;
        size_t g = ((size_t)b * TT + r * 16 + p) * 768 + 256 + h * 64 + q * 8;
        u16x8 v = *(const u16x8*)&QKV[g];
        u16x4 lo = {v[0], v[1], v[2], v[3]}, hi = {v[4], v[5], v[6], v[7]};
        *(u16x4*)&KV[r * 68 + q * 8] = lo;
        *(u16x4*)&KV[r * 68 + q * 8 + 4] = hi;
    }
    __syncthreads();
    float sc[8];
    float mx = -1e30f;
    #pragma unroll
    for (int kk = 0; kk < 8; kk++) {
        int row = s - 7 + kk;
        float a = -1e30f;
        if (row >= 0) {
            a = 0.f;
            const u16* kr = &KV[row * 68];
            #pragma unroll
            for (int d = 0; d < 32; d++) {
                u16x2 u = *(const u16x2*)&kr[d * 2];
                a += qv[d * 2] * b2f(u[0]) + qv[d * 2 + 1] * b2f(u[1]);
            }
            a *= 0.125f;
        }
        sc[kk] = a;
        mx = fmaxf(mx, a);
    }
    float se = 0.f;
    #pragma unroll
    for (int kk = 0; kk < 8; kk++) {
        float e = (sc[kk] > -1e29f) ? __expf(sc[kk] - mx) : 0.f;
        sc[kk] = e; se += e;
    }
    const float inv = 1.f / se;
    __syncthreads();
    for (int u = tid; u < 2048; u += 256) {
        int r = u >> 3, q = u & 7;
        size_t g = ((size_t)b * TT + r * 16 + p) * 768 + 512 + h * 64 + q * 8;
        u16x8 v = *(const u16x8*)&QKV[g];
        u16x4 lo = {v[0], v[1], v[2], v[3]}, hi = {v[4], v[5], v[6], v[7]};
        *(u16x4*)&KV[r * 68 + q * 8] = lo;
        *(u16x4*)&KV[r * 68 + q * 8 + 4] = hi;
    }
    __syncthreads();
    float ov[64];
    #pragma unroll
    for (int d = 0; d < 64; d++) ov[d] = 0.f;
    #pragma unroll
    for (int kk = 0; kk < 8; kk++) {
        int row = s - 7 + kk;
        if (row >= 0) {
            float w = sc[kk] * inv;
            const u16* vr = &KV[row * 68];
            #pragma unroll
            for (int d = 0; d < 32; d++) {
                u16x2 u = *(const u16x2*)&vr[d * 2];
                ov[d * 2]     += w * b2f(u[0]);
                ov[d * 2 + 1] += w * b2f(u[1]);
            }
        }
    }
    size_t og = ((size_t)b * TT + s * 16 + p) * 256 + h * 64;
    #pragma unroll
    for (int d4 = 0; d4 < 16; d4++) {
        u16x4 o = {f2b(ov[d4 * 4]), f2b(ov[d4 * 4 + 1]), f2b(ov[d4 * 4 + 2]), f2b(ov[d4 * 4 + 3])};
        *(u16x4*)&O[og + d4 * 4] = o;
    }
}

extern "C" void kernel_launch(void* const* d_in, const int* in_sizes, int n_in,
                              void* d_out, int out_size, void* d_ws, size_t ws_size,
                              hipStream_t stream)
{
    const float* z        = (const float*)d_in[0];
    const float* tb0_b1   = (const float*)d_in[2];
    const float* tb0_b2   = (const float*)d_in[4];
    const float* tb0_bd   = (const float*)d_in[6];
    const float* tb1_b1   = (const float*)d_in[8];
    const float* tb1_b2   = (const float*)d_in[10];
    const float* tb2_b1   = (const float*)d_in[12];
    const float* tb2_b2   = (const float*)d_in[14];
    const float* tb3_b1   = (const float*)d_in[16];
    const float* tb3_b2   = (const float*)d_in[18];
    const float* attn_in_b  = (const float*)d_in[20];
    const float* attn_out_b = (const float*)d_in[22];
    const float* ln1_g = (const float*)d_in[23];
    const float* ln1_b = (const float*)d_in[24];
    const float* ln2_g = (const float*)d_in[25];
    const float* ln2_b = (const float*)d_in[26];
    const float* ffn_b1 = (const float*)d_in[28];
    const float* ffn_b2 = (const float*)d_in[30];
    const float* last_w = (const float*)d_in[31];
    const float* last_b = (const float*)d_in[32];
    (void)in_sizes; (void)n_in; (void)out_size;

    const size_t MB = 1ull << 20;
    int Bc = 0;
    for (int c = 32; c >= 1; c >>= 1) {
        if (ws_size >= (4 + 12 * (size_t)c) * MB) { Bc = c; break; }
    }
    if (Bc == 0) return;

    char* ws = (char*)d_ws;
    u16* WBp = (u16*)ws;
    u16* zp  = (u16*)(ws + 3 * MB);
    u16* U1  = (u16*)(ws + 4 * MB);
    u16* U2  = (u16*)(ws + (4 + 2 * (size_t)Bc) * MB);
    u16* U3  = (u16*)(ws + (4 + 4 * (size_t)Bc) * MB);
    u16* Q   = (u16*)(ws + (4 + 6 * (size_t)Bc) * MB);
    u16* Z   = Q;
    u16* F   = Q;
    float* outp = (float*)d_out;

    dim3 b256(256), b512(512);
    hipMemsetAsync((void*)zp, 0, 4096, stream);
    prep_weights<<<dim3(768, 13), b256, 0, stream>>>(
        (const float*)d_in[1], (const float*)d_in[3], (const float*)d_in[5],
        (const float*)d_in[7], (const float*)d_in[9], (const float*)d_in[11],
        (const float*)d_in[13], (const float*)d_in[15], (const float*)d_in[17],
        (const float*)d_in[19], (const float*)d_in[21],
        (const float*)d_in[27], (const float*)d_in[29], WBp);

    const int nchunk = 32 / Bc;
    for (int c = 0; c < nchunk; c++) {
        const float* zc = z + (size_t)c * Bc * 128 * TT;
        float* oc = outp + (size_t)c * Bc * TT;

        transpose_z<<<dim3(64, 4, Bc), b256, 0, stream>>>(zc, Z);

        // --- TCN block 0 (k=1 convs + downsample) ---
        gemm512<1, 0, 0><<<dim3(32, 1, Bc), b512, 0, stream>>>(Z, WBp + W_TB0_1, 128, 256,
            tb0_b1, nullptr, U1, nullptr, nullptr, nullptr, nullptr, nullptr);
        gemm512<1, 0, 0><<<dim3(32, 1, Bc), b512, 0, stream>>>(U1, WBp + W_TB0_2, 256, 256,
            tb0_b2, nullptr, U2, nullptr, nullptr, nullptr, nullptr, nullptr);
        gemm512<1, 1, 0><<<dim3(32, 1, Bc), b512, 0, stream>>>(Z, WBp + W_TB0_D, 128, 256,
            tb0_bd, U2, U3, nullptr, nullptr, nullptr, nullptr, nullptr);
        // --- TCN blocks 1..3 (k=2, dil 1/2/4) ---
        gemm_dual<0><<<dim3(32, 2, Bc), b256, 0, stream>>>(U3, WBp + W_TB1_1_T1, 256,
            WBp + W_TB1_1_T0, 1, tb1_b1, nullptr, U1, zp);
        gemm_dual<2><<<dim3(32, 2, Bc), b256, 0, stream>>>(U1, WBp + W_TB1_2_T1, 256,
            WBp + W_TB1_2_T0, 1, tb1_b2, U3, U2, zp);
        gemm_dual<0><<<dim3(32, 2, Bc), b256, 0, stream>>>(U2, WBp + W_TB2_1_T1, 256,
            WBp + W_TB2_1_T0, 2, tb2_b1, nullptr, U1, zp);
        gemm_dual<2><<<dim3(32, 2, Bc), b256, 0, stream>>>(U1, WBp + W_TB2_2_T1, 256,
            WBp + W_TB2_2_T0, 2, tb2_b2, U2, U3, zp);
        gemm_dual<0><<<dim3(32, 2, Bc), b256, 0, stream>>>(U3, WBp + W_TB3_1_T1, 256,
            WBp + W_TB3_1_T0, 4, tb3_b1, nullptr, U1, zp);
        gemm_dual<2><<<dim3(32, 2, Bc), b256, 0, stream>>>(U1, WBp + W_TB3_2_T1, 256,
            WBp + W_TB3_2_T0, 4, tb3_b2, U3, U2, zp);
        // --- attention ---
        gemm512<0, 0, 0><<<dim3(32, 3, Bc), b512, 0, stream>>>(U2, WBp + W_ATTN_IN, 256, 768,
            attn_in_b, nullptr, Q, nullptr, nullptr, nullptr, nullptr, nullptr);
        attn_win<<<dim3(16, 4, Bc), b256, 0, stream>>>(Q, U3);
        // attn_out GEMM + residual(x4) + LN1 -> xn
        gemm512<0, 0, 1><<<dim3(32, 1, Bc), b512, 0, stream>>>(U3, WBp + W_ATTN_OUT, 256, 256,
            attn_out_b, U2, U1, ln1_g, ln1_b, nullptr, nullptr, nullptr);
        // --- FFN ---
        gemm512<2, 0, 0><<<dim3(32, 2, Bc), b512, 0, stream>>>(U1, WBp + W_FFN1, 256, 512,
            ffn_b1, nullptr, F, nullptr, nullptr, nullptr, nullptr, nullptr);
        // FFN2 + residual(xn) + LN2 + final projection -> out
        gemm512<0, 0, 2><<<dim3(32, 1, Bc), b512, 0, stream>>>(F, WBp + W_FFN2, 512, 256,
            ffn_b2, U1, nullptr, ln2_g, ln2_b, last_w, last_b, oc);
    }
}

// Round 7
// 911.979 us; speedup vs baseline: 1.0534x; 1.0534x over previous
//
#include <hip/hip_runtime.h>
#include <cmath>

#define BB 32
#define TT 4096

typedef unsigned short u16;
typedef __attribute__((ext_vector_type(8))) __bf16 bf16x8;
typedef __attribute__((ext_vector_type(4))) float f32x4;
typedef __attribute__((ext_vector_type(8))) unsigned short u16x8;
typedef __attribute__((ext_vector_type(4))) unsigned short u16x4;
typedef __attribute__((ext_vector_type(2))) unsigned short u16x2;
typedef __attribute__((ext_vector_type(4))) unsigned int u32x4;

typedef __attribute__((address_space(3))) unsigned int lds_uint;
typedef __attribute__((address_space(1))) unsigned int g_uint;

__device__ __forceinline__ void gl_lds16(const void* g, void* l) {
    __builtin_amdgcn_global_load_lds((const g_uint*)g, (lds_uint*)l, 16, 0, 0);
}

__device__ __forceinline__ u16 f2b(float x) {
    unsigned u = __builtin_bit_cast(unsigned, x);
    return (u16)((u + 0x7fffu + ((u >> 16) & 1u)) >> 16);
}
__device__ __forceinline__ float b2f(u16 h) {
    unsigned u = ((unsigned)h) << 16;
    return __builtin_bit_cast(float, u);
}
__device__ __forceinline__ unsigned pkbf(float a, float b) {
    unsigned ua = __builtin_bit_cast(unsigned, a) + 0x8000u;
    unsigned ub = __builtin_bit_cast(unsigned, b) + 0x8000u;
    return __builtin_amdgcn_perm(ub, ua, 0x07060302);
}

// ---- bf16 weight area offsets (elements) ----
enum : int {
  W_TB0_1 = 0,
  W_TB0_2 = 32768,
  W_TB0_D = 98304,
  W_TB1_1_T0 = 131072, W_TB1_1_T1 = 196608,
  W_TB1_2_T0 = 262144, W_TB1_2_T1 = 327680,
  W_TB2_1_T0 = 393216, W_TB2_1_T1 = 458752,
  W_TB2_2_T0 = 524288, W_TB2_2_T1 = 589824,
  W_TB3_1_T0 = 655360, W_TB3_1_T1 = 720896,
  W_TB3_2_T0 = 786432, W_TB3_2_T1 = 851968,
  W_ATTN_IN  = 917504,
  W_ATTN_OUT = 1114112,
  W_FFN1     = 1179648,
  W_FFN2     = 1310720,
};

__global__ __launch_bounds__(256)
void prep_weights(const float* s0, const float* s1, const float* s2,
                  const float* s3, const float* s4, const float* s5,
                  const float* s6, const float* s7, const float* s8,
                  const float* s9, const float* s10, const float* s11,
                  const float* s12, u16* wb)
{
    int seg = blockIdx.y;
    int i = blockIdx.x * 256 + threadIdx.x;
    switch (seg) {
    case 0:  if (i < 32768)  wb[W_TB0_1 + i] = f2b(s0[i]); break;
    case 1:  if (i < 65536)  wb[W_TB0_2 + i] = f2b(s1[i]); break;
    case 2:  if (i < 32768)  wb[W_TB0_D + i] = f2b(s2[i]); break;
    case 3:  if (i < 65536) { wb[W_TB1_1_T0 + i] = f2b(s3[2*i]); wb[W_TB1_1_T1 + i] = f2b(s3[2*i+1]); } break;
    case 4:  if (i < 65536) { wb[W_TB1_2_T0 + i] = f2b(s4[2*i]); wb[W_TB1_2_T1 + i] = f2b(s4[2*i+1]); } break;
    case 5:  if (i < 65536) { wb[W_TB2_1_T0 + i] = f2b(s5[2*i]); wb[W_TB2_1_T1 + i] = f2b(s5[2*i+1]); } break;
    case 6:  if (i < 65536) { wb[W_TB2_2_T0 + i] = f2b(s6[2*i]); wb[W_TB2_2_T1 + i] = f2b(s6[2*i+1]); } break;
    case 7:  if (i < 65536) { wb[W_TB3_1_T0 + i] = f2b(s7[2*i]); wb[W_TB3_1_T1 + i] = f2b(s7[2*i+1]); } break;
    case 8:  if (i < 65536) { wb[W_TB3_2_T0 + i] = f2b(s8[2*i]); wb[W_TB3_2_T1 + i] = f2b(s8[2*i+1]); } break;
    case 9:  if (i < 196608) wb[W_ATTN_IN + i]  = f2b(s9[i]);  break;
    case 10: if (i < 65536)  wb[W_ATTN_OUT + i] = f2b(s10[i]); break;
    case 11: if (i < 131072) wb[W_FFN1 + i]     = f2b(s11[i]); break;
    case 12: if (i < 131072) wb[W_FFN2 + i]     = f2b(s12[i]); break;
    }
}

// z [Bc,128,T] fp32 -> Z [Bc,T,128] bf16 (token-major)
__global__ __launch_bounds__(256)
void transpose_z(const float* __restrict__ z, u16* __restrict__ Z)
{
    __shared__ u16 tile[64][33];
    const int t0 = blockIdx.x << 6;
    const int c0 = blockIdx.y << 5;
    const int b  = blockIdx.z;
    const int tid = threadIdx.x;
    #pragma unroll
    for (int r = 0; r < 8; r++) {
        int lin = r * 256 + tid;
        int cc = lin >> 6, tt = lin & 63;
        tile[tt][cc] = f2b(z[((size_t)b * 128 + c0 + cc) * TT + t0 + tt]);
    }
    __syncthreads();
    #pragma unroll
    for (int r = 0; r < 8; r++) {
        int lin = r * 256 + tid;
        int tt = lin >> 5, cc = lin & 31;
        Z[((size_t)b * TT + t0 + tt) * 128 + c0 + cc] = tile[tt][cc];
    }
}

// Swizzled LDS fragment address: rows of 128B (8 chunks of 16B); physical chunk = logical ^ (row&7)
__device__ __forceinline__ const bf16x8* lds_frag(const u16* base, int row, int lc) {
    return (const bf16x8*)((const char*)base + row * 128 + (((lc ^ row) & 7) << 4) + ((lc & ~7) << 4));
}

// ===================== 256-thread 64-token x 256-channel GEMM =====================
// 4 waves; wave wv covers all 64 tokens x channels [64*wv, 64*wv+64).
//   Y[b,t,n0+m] = epi( sum_k X[b,t,k]*W[n0+m,k] + bias[n0+m] )
// ACT (EPI==0): 0 none, 1 relu, 2 gelu.  RMODE==1: v = act(acc + res).
// EPI: 0 plain store; 1 LN(acc+res)->store; 2 LN(acc+res)->dot(lw)+lb->out fp32.
template<int ACT, int RMODE, int EPI>
__global__ __launch_bounds__(256)
void gemm64(const u16* __restrict__ X, const u16* __restrict__ W, int K, int M,
            const float* __restrict__ bias,
            const u16* __restrict__ res, u16* __restrict__ Y,
            const float* __restrict__ g, const float* __restrict__ be,
            const float* __restrict__ lw, const float* __restrict__ lb,
            float* __restrict__ out)
{
    __shared__ __align__(16) char smem[40960];   // Xs 8K + Ws 32K; CT (33280B) overlays
    u16* Xs = (u16*)smem;
    u16* Ws = (u16*)(smem + 8192);
    float (*CT)[260] = (float(*)[260])smem;

    const int tid = threadIdx.x;
    const int b  = blockIdx.z;
    const int t0 = blockIdx.x << 6;
    const int n0 = blockIdx.y << 8;
    const int lane = tid & 63;
    const int wv = tid >> 6;
    const int wn = wv << 6;             // wave channel-offset 0..192
    const int l15 = lane & 15;
    const int quad = lane >> 4;

    // staging descriptors
    const char* xsrc[2]; char* xdst[2];
    #pragma unroll
    for (int u = 0; u < 2; u++) {
        const int c = tid + (u << 8);
        const int r = c >> 3, q = (c & 7) ^ (r & 7);
        xdst[u] = (char*)Xs + c * 16;
        xsrc[u] = (const char*)(X + ((size_t)b * TT + t0 + r) * K + q * 8);
    }
    const char* wsrc[8]; char* wdst[8];
    #pragma unroll
    for (int u = 0; u < 8; u++) {
        const int c = tid + (u << 8);
        const int r = c >> 3, q = (c & 7) ^ (r & 7);
        wdst[u] = (char*)Ws + c * 16;
        wsrc[u] = (const char*)(W + (size_t)(n0 + r) * K + q * 8);
    }

    f32x4 acc[4][4];
    #pragma unroll
    for (int j = 0; j < 4; j++) {
        const f32x4 bj = *(const f32x4*)&bias[n0 + wn + j * 16 + quad * 4];
        #pragma unroll
        for (int i = 0; i < 4; i++) acc[i][j] = bj;
    }

    for (int k0 = 0; k0 < K; k0 += 64) {
        #pragma unroll
        for (int u = 0; u < 2; u++) gl_lds16(xsrc[u] + 2 * k0, xdst[u]);
        #pragma unroll
        for (int u = 0; u < 8; u++) gl_lds16(wsrc[u] + 2 * k0, wdst[u]);
        __syncthreads();
        #pragma unroll
        for (int ks = 0; ks < 2; ks++) {
            const int lc = ks * 4 + quad;
            bf16x8 af[4], bw[4];
            #pragma unroll
            for (int i = 0; i < 4; i++)
                af[i] = *lds_frag(Xs, i * 16 + l15, lc);
            #pragma unroll
            for (int j = 0; j < 4; j++)
                bw[j] = *lds_frag(Ws, wn + j * 16 + l15, lc);
            #pragma unroll
            for (int i = 0; i < 4; i++)
                #pragma unroll
                for (int j = 0; j < 4; j++)
                    acc[i][j] = __builtin_amdgcn_mfma_f32_16x16x32_bf16(bw[j], af[i], acc[i][j], 0, 0, 0);
        }
        __syncthreads();
    }

    // ---- epilogue: 2 phases of 32 tokens; CT with +8*tt column rotation ----
    #pragma unroll
    for (int h = 0; h < 2; h++) {
        #pragma unroll
        for (int i2 = 0; i2 < 2; i2++) {
            const int tt = i2 * 16 + l15;
            #pragma unroll
            for (int j = 0; j < 4; j++) {
                const int c = wn + j * 16 + quad * 4;
                const int pc = (c + 8 * tt) & 255;
                *(f32x4*)&CT[tt][pc] = acc[h * 2 + i2][j];
            }
        }
        __syncthreads();
        #pragma unroll
        for (int r4 = 0; r4 < 4; r4++) {
            const int lin = (r4 << 8) + tid;
            const int tt = lin >> 5;            // 0..31
            const int ck = lin & 31;            // 8-ch chunk
            const int pcc = ((ck + tt) & 31) << 3;
            const int token = t0 + h * 32 + tt;
            const int gc = n0 + ck * 8;
            f32x4 v0 = *(const f32x4*)&CT[tt][pcc];
            f32x4 v1 = *(const f32x4*)&CT[tt][pcc + 4];
            if (RMODE == 1 || EPI >= 1) {
                const u16x8 rv = *(const u16x8*)&res[((size_t)b * TT + token) * 256 + ck * 8];
                #pragma unroll
                for (int e = 0; e < 4; e++) { v0[e] += b2f(rv[e]); v1[e] += b2f(rv[e + 4]); }
            }
            if (EPI == 0) {
                if (ACT == 1) {
                    #pragma unroll
                    for (int e = 0; e < 4; e++) { v0[e] = fmaxf(v0[e], 0.f); v1[e] = fmaxf(v1[e], 0.f); }
                }
                if (ACT == 2) {
                    #pragma unroll
                    for (int e = 0; e < 4; e++) {
                        v0[e] = 0.5f * v0[e] * (1.f + erff(v0[e] * 0.70710678118f));
                        v1[e] = 0.5f * v1[e] * (1.f + erff(v1[e] * 0.70710678118f));
                    }
                }
                u32x4 po;
                po[0] = pkbf(v0[0], v0[1]); po[1] = pkbf(v0[2], v0[3]);
                po[2] = pkbf(v1[0], v1[1]); po[3] = pkbf(v1[2], v1[3]);
                *(u32x4*)&Y[((size_t)b * TT + token) * M + gc] = po;
            } else {
                // LayerNorm over 256 channels: 32 consecutive lanes share a token
                float s = 0.f, sq = 0.f;
                #pragma unroll
                for (int e = 0; e < 4; e++) {
                    s += v0[e] + v1[e];
                    sq += v0[e] * v0[e] + v1[e] * v1[e];
                }
                #pragma unroll
                for (int off = 16; off >= 1; off >>= 1) {
                    s += __shfl_xor(s, off, 64);
                    sq += __shfl_xor(sq, off, 64);
                }
                const float mean = s * (1.f / 256.f);
                const float var = sq * (1.f / 256.f) - mean * mean;
                const float rstd = rsqrtf(var + 1e-5f);
                const f32x4 g0 = *(const f32x4*)&g[gc];
                const f32x4 g1 = *(const f32x4*)&g[gc + 4];
                const f32x4 be0 = *(const f32x4*)&be[gc];
                const f32x4 be1 = *(const f32x4*)&be[gc + 4];
                f32x4 x0, x1;
                #pragma unroll
                for (int e = 0; e < 4; e++) {
                    x0[e] = (v0[e] - mean) * rstd * g0[e] + be0[e];
                    x1[e] = (v1[e] - mean) * rstd * g1[e] + be1[e];
                }
                if (EPI == 1) {
                    u32x4 po;
                    po[0] = pkbf(x0[0], x0[1]); po[1] = pkbf(x0[2], x0[3]);
                    po[2] = pkbf(x1[0], x1[1]); po[3] = pkbf(x1[2], x1[3]);
                    *(u32x4*)&Y[((size_t)b * TT + token) * 256 + gc] = po;
                } else {
                    const f32x4 w0 = *(const f32x4*)&lw[gc];
                    const f32x4 w1 = *(const f32x4*)&lw[gc + 4];
                    float a = 0.f;
                    #pragma unroll
                    for (int e = 0; e < 4; e++) a += x0[e] * w0[e] + x1[e] * w1[e];
                    #pragma unroll
                    for (int off = 16; off >= 1; off >>= 1) a += __shfl_xor(a, off, 64);
                    if ((lane & 31) == 0) out[(size_t)b * TT + token] = a + lb[0];
                }
            }
        }
        __syncthreads();
    }
}

// ===================== dual-tap conv GEMM (proven, unchanged) =====================
template<int RMODE>
__global__ __launch_bounds__(256)
void gemm_dual(const u16* __restrict__ X, const u16* __restrict__ W1, int K,
               const u16* __restrict__ W2, int sh,
               const float* __restrict__ bias1,
               const u16* __restrict__ res, u16* __restrict__ Y,
               const u16* __restrict__ zp)
{
    constexpr int XR = 132;
    constexpr int STB = (XR + 256) * 128;
    constexpr int SMB = STB > 33792 ? STB : 33792;
    __shared__ __align__(16) char smem[SMB];
    u16* Xs = (u16*)smem;
    u16* Ws = (u16*)(smem + XR * 128);
    float (*CT)[132] = (float(*)[132])smem;

    const int tid = threadIdx.x;
    const int b  = blockIdx.z;
    const int t0 = blockIdx.x << 7;
    const int n0 = blockIdx.y << 7;
    const int lane = tid & 63;
    const int wv = tid >> 6;
    const int wt = (wv >> 1) << 6;
    const int wn = (wv & 1) << 6;
    const int l15 = lane & 15;
    const int quad = lane >> 4;
    const int shl = sh;

    const char* xsrc[4]; char* xdst[4];
    #pragma unroll
    for (int u = 0; u < 4; u++) {
        const int c = tid + (u << 8);
        const int r = c >> 3, p = c & 7, q = p ^ (r & 7);
        const int st = t0 + r - shl;
        xdst[u] = (char*)Xs + c * 16;
        xsrc[u] = (const char*)((st >= 0 ? (X + ((size_t)b * TT + st) * K) : zp) + q * 8);
    }
    const char* wsrc[8]; char* wdst[8];
    #pragma unroll
    for (int u = 0; u < 8; u++) {
        const int c = tid + (u << 8);
        const int r = c >> 3, p = c & 7, q = p ^ (r & 7);
        wdst[u] = (char*)Ws + c * 16;
        const u16* wb_ = (r >= 128) ? (W2 + (size_t)(n0 + r - 128) * K)
                                    : (W1 + (size_t)(n0 + r) * K);
        wsrc[u] = (const char*)(wb_ + q * 8);
    }
    const u16* hsrc = nullptr; u16* hdst = nullptr;
    if (tid < 8 * shl) {
        const int hr = 128 + (tid >> 3), hp = tid & 7, hq = hp ^ (hr & 7);
        hsrc = X + ((size_t)b * TT + t0 + hr - shl) * K + hq * 8;
        hdst = (u16*)((char*)Xs + (1024 + tid) * 16);
    }

    f32x4 acc[4][4];
    #pragma unroll
    for (int j = 0; j < 4; j++) {
        const f32x4 bj = *(const f32x4*)&bias1[n0 + wn + j * 16 + quad * 4];
        #pragma unroll
        for (int i = 0; i < 4; i++) acc[i][j] = bj;
    }

    for (int k0 = 0; k0 < K; k0 += 64) {
        #pragma unroll
        for (int u = 0; u < 4; u++) gl_lds16(xsrc[u] + 2 * k0, xdst[u]);
        #pragma unroll
        for (int u = 0; u < 8; u++) gl_lds16(wsrc[u] + 2 * k0, wdst[u]);
        if (hdst) *(u16x8*)hdst = *(const u16x8*)(hsrc + k0);
        __syncthreads();
        #pragma unroll
        for (int ks = 0; ks < 2; ks++) {
            bf16x8 af[4], bw[4];
            const int lc = ks * 4 + quad;
            #pragma unroll
            for (int i = 0; i < 4; i++)
                af[i] = *lds_frag(Xs, shl + wt + i * 16 + l15, lc);
            #pragma unroll
            for (int j = 0; j < 4; j++)
                bw[j] = *lds_frag(Ws, wn + j * 16 + l15, lc);
            #pragma unroll
            for (int i = 0; i < 4; i++)
                #pragma unroll
                for (int j = 0; j < 4; j++)
                    acc[i][j] = __builtin_amdgcn_mfma_f32_16x16x32_bf16(bw[j], af[i], acc[i][j], 0, 0, 0);
            #pragma unroll
            for (int i = 0; i < 4; i++)
                af[i] = *lds_frag(Xs, wt + i * 16 + l15, lc);
            #pragma unroll
            for (int j = 0; j < 4; j++)
                bw[j] = *lds_frag(Ws, 128 + wn + j * 16 + l15, lc);
            #pragma unroll
            for (int i = 0; i < 4; i++)
                #pragma unroll
                for (int j = 0; j < 4; j++)
                    acc[i][j] = __builtin_amdgcn_mfma_f32_16x16x32_bf16(bw[j], af[i], acc[i][j], 0, 0, 0);
        }
        __syncthreads();
    }

    #pragma unroll
    for (int h = 0; h < 2; h++) {
        if (wt == h * 64) {
            #pragma unroll
            for (int i = 0; i < 4; i++) {
                const int tt = i * 16 + l15;
                #pragma unroll
                for (int j = 0; j < 4; j++)
                    *(f32x4*)&CT[tt][wn + j * 16 + quad * 4] = acc[i][j];
            }
        }
        __syncthreads();
        #pragma unroll
        for (int r4 = 0; r4 < 4; r4++) {
            const int lin = (r4 << 8) + tid;
            const int tt = lin >> 4;
            const int ck = lin & 15;
            const int gr = t0 + h * 64 + tt;
            const int gc = n0 + ck * 8;
            const size_t oidx = ((size_t)b * TT + gr) * 256 + gc;
            f32x4 v0 = *(const f32x4*)&CT[tt][ck * 8];
            f32x4 v1 = *(const f32x4*)&CT[tt][ck * 8 + 4];
            if (RMODE == 2) {
                const u16x8 rv = *(const u16x8*)&res[oidx];
                #pragma unroll
                for (int e = 0; e < 4; e++) {
                    v0[e] = fmaxf(fmaxf(v0[e], 0.f) + b2f(rv[e]), 0.f);
                    v1[e] = fmaxf(fmaxf(v1[e], 0.f) + b2f(rv[e + 4]), 0.f);
                }
            } else {
                #pragma unroll
                for (int e = 0; e < 4; e++) { v0[e] = fmaxf(v0[e], 0.f); v1[e] = fmaxf(v1[e], 0.f); }
            }
            u32x4 po;
            po[0] = pkbf(v0[0], v0[1]); po[1] = pkbf(v0[2], v0[3]);
            po[2] = pkbf(v1[0], v1[1]); po[3] = pkbf(v1[2], v1[3]);
            *(u32x4*)&Y[oidx] = po;
        }
        if (h == 0) __syncthreads();
    }
}

// Sliding-window causal attention, window 8, one block per (p, h, b), one query per thread.
__global__ __launch_bounds__(256)
void attn_win(const u16* __restrict__ QKV, u16* __restrict__ O)
{
    __shared__ u16 KV[256 * 68];
    const int p = blockIdx.x, h = blockIdx.y, b = blockIdx.z;
    const int tid = threadIdx.x;
    const int s = tid;

    float qv[64];
    {
        size_t qg = ((size_t)b * TT + s * 16 + p) * 768 + h * 64;
        #pragma unroll
        for (int c = 0; c < 8; c++) {
            u16x8 u = *(const u16x8*)&QKV[qg + c * 8];
            #pragma unroll
            for (int j = 0; j < 8; j++) qv[c * 8 + j] = b2f(u[j]);
        }
    }
    for (int u = tid; u < 2048; u += 256) {
        int r = u >> 3, q = u & 7;
        size_t g = ((size_t)b * TT + r * 16 + p) * 768 + 256 + h * 64 + q * 8;
        u16x8 v = *(const u16x8*)&QKV[g];
        u16x4 lo = {v[0], v[1], v[2], v[3]}, hi = {v[4], v[5], v[6], v[7]};
        *(u16x4*)&KV[r * 68 + q * 8] = lo;
        *(u16x4*)&KV[r * 68 + q * 8 + 4] = hi;
    }
    __syncthreads();
    float sc[8];
    float mx = -1e30f;
    #pragma unroll
    for (int kk = 0; kk < 8; kk++) {
        int row = s - 7 + kk;
        float a = -1e30f;
        if (row >= 0) {
            a = 0.f;
            const u16* kr = &KV[row * 68];
            #pragma unroll
            for (int d = 0; d < 32; d++) {
                u16x2 u = *(const u16x2*)&kr[d * 2];
                a += qv[d * 2] * b2f(u[0]) + qv[d * 2 + 1] * b2f(u[1]);
            }
            a *= 0.125f;
        }
        sc[kk] = a;
        mx = fmaxf(mx, a);
    }
    float se = 0.f;
    #pragma unroll
    for (int kk = 0; kk < 8; kk++) {
        float e = (sc[kk] > -1e29f) ? __expf(sc[kk] - mx) : 0.f;
        sc[kk] = e; se += e;
    }
    const float inv = 1.f / se;
    __syncthreads();
    for (int u = tid; u < 2048; u += 256) {
        int r = u >> 3, q = u & 7;
        size_t g = ((size_t)b * TT + r * 16 + p) * 768 + 512 + h * 64 + q * 8;
        u16x8 v = *(const u16x8*)&QKV[g];
        u16x4 lo = {v[0], v[1], v[2], v[3]}, hi = {v[4], v[5], v[6], v[7]};
        *(u16x4*)&KV[r * 68 + q * 8] = lo;
        *(u16x4*)&KV[r * 68 + q * 8 + 4] = hi;
    }
    __syncthreads();
    float ov[64];
    #pragma unroll
    for (int d = 0; d < 64; d++) ov[d] = 0.f;
    #pragma unroll
    for (int kk = 0; kk < 8; kk++) {
        int row = s - 7 + kk;
        if (row >= 0) {
            float w = sc[kk] * inv;
            const u16* vr = &KV[row * 68];
            #pragma unroll
            for (int d = 0; d < 32; d++) {
                u16x2 u = *(const u16x2*)&vr[d * 2];
                ov[d * 2]     += w * b2f(u[0]);
                ov[d * 2 + 1] += w * b2f(u[1]);
            }
        }
    }
    size_t og = ((size_t)b * TT + s * 16 + p) * 256 + h * 64;
    #pragma unroll
    for (int d4 = 0; d4 < 16; d4++) {
        u16x4 o = {f2b(ov[d4 * 4]), f2b(ov[d4 * 4 + 1]), f2b(ov[d4 * 4 + 2]), f2b(ov[d4 * 4 + 3])};
        *(u16x4*)&O[og + d4 * 4] = o;
    }
}

extern "C" void kernel_launch(void* const* d_in, const int* in_sizes, int n_in,
                              void* d_out, int out_size, void* d_ws, size_t ws_size,
                              hipStream_t stream)
{
    const float* z        = (const float*)d_in[0];
    const float* tb0_b1   = (const float*)d_in[2];
    const float* tb0_b2   = (const float*)d_in[4];
    const float* tb0_bd   = (const float*)d_in[6];
    const float* tb1_b1   = (const float*)d_in[8];
    const float* tb1_b2   = (const float*)d_in[10];
    const float* tb2_b1   = (const float*)d_in[12];
    const float* tb2_b2   = (const float*)d_in[14];
    const float* tb3_b1   = (const float*)d_in[16];
    const float* tb3_b2   = (const float*)d_in[18];
    const float* attn_in_b  = (const float*)d_in[20];
    const float* attn_out_b = (const float*)d_in[22];
    const float* ln1_g = (const float*)d_in[23];
    const float* ln1_b = (const float*)d_in[24];
    const float* ln2_g = (const float*)d_in[25];
    const float* ln2_b = (const float*)d_in[26];
    const float* ffn_b1 = (const float*)d_in[28];
    const float* ffn_b2 = (const float*)d_in[30];
    const float* last_w = (const float*)d_in[31];
    const float* last_b = (const float*)d_in[32];
    (void)in_sizes; (void)n_in; (void)out_size;

    const size_t MB = 1ull << 20;
    int Bc = 0;
    for (int c = 32; c >= 1; c >>= 1) {
        if (ws_size >= (4 + 12 * (size_t)c) * MB) { Bc = c; break; }
    }
    if (Bc == 0) return;

    char* ws = (char*)d_ws;
    u16* WBp = (u16*)ws;
    u16* zp  = (u16*)(ws + 3 * MB);
    u16* U1  = (u16*)(ws + 4 * MB);
    u16* U2  = (u16*)(ws + (4 + 2 * (size_t)Bc) * MB);
    u16* U3  = (u16*)(ws + (4 + 4 * (size_t)Bc) * MB);
    u16* Q   = (u16*)(ws + (4 + 6 * (size_t)Bc) * MB);
    u16* Z   = Q;
    u16* F   = Q;
    float* outp = (float*)d_out;

    dim3 b256(256);
    hipMemsetAsync((void*)zp, 0, 4096, stream);
    prep_weights<<<dim3(768, 13), b256, 0, stream>>>(
        (const float*)d_in[1], (const float*)d_in[3], (const float*)d_in[5],
        (const float*)d_in[7], (const float*)d_in[9], (const float*)d_in[11],
        (const float*)d_in[13], (const float*)d_in[15], (const float*)d_in[17],
        (const float*)d_in[19], (const float*)d_in[21],
        (const float*)d_in[27], (const float*)d_in[29], WBp);

    const int nchunk = 32 / Bc;
    for (int c = 0; c < nchunk; c++) {
        const float* zc = z + (size_t)c * Bc * 128 * TT;
        float* oc = outp + (size_t)c * Bc * TT;

        transpose_z<<<dim3(64, 4, Bc), b256, 0, stream>>>(zc, Z);

        // --- TCN block 0 (k=1 convs + downsample) ---
        gemm64<1, 0, 0><<<dim3(64, 1, Bc), b256, 0, stream>>>(Z, WBp + W_TB0_1, 128, 256,
            tb0_b1, nullptr, U1, nullptr, nullptr, nullptr, nullptr, nullptr);
        gemm64<1, 0, 0><<<dim3(64, 1, Bc), b256, 0, stream>>>(U1, WBp + W_TB0_2, 256, 256,
            tb0_b2, nullptr, U2, nullptr, nullptr, nullptr, nullptr, nullptr);
        gemm64<1, 1, 0><<<dim3(64, 1, Bc), b256, 0, stream>>>(Z, WBp + W_TB0_D, 128, 256,
            tb0_bd, U2, U3, nullptr, nullptr, nullptr, nullptr, nullptr);
        // --- TCN blocks 1..3 (k=2, dil 1/2/4) ---
        gemm_dual<0><<<dim3(32, 2, Bc), b256, 0, stream>>>(U3, WBp + W_TB1_1_T1, 256,
            WBp + W_TB1_1_T0, 1, tb1_b1, nullptr, U1, zp);
        gemm_dual<2><<<dim3(32, 2, Bc), b256, 0, stream>>>(U1, WBp + W_TB1_2_T1, 256,
            WBp + W_TB1_2_T0, 1, tb1_b2, U3, U2, zp);
        gemm_dual<0><<<dim3(32, 2, Bc), b256, 0, stream>>>(U2, WBp + W_TB2_1_T1, 256,
            WBp + W_TB2_1_T0, 2, tb2_b1, nullptr, U1, zp);
        gemm_dual<2><<<dim3(32, 2, Bc), b256, 0, stream>>>(U1, WBp + W_TB2_2_T1, 256,
            WBp + W_TB2_2_T0, 2, tb2_b2, U2, U3, zp);
        gemm_dual<0><<<dim3(32, 2, Bc), b256, 0, stream>>>(U3, WBp + W_TB3_1_T1, 256,
            WBp + W_TB3_1_T0, 4, tb3_b1, nullptr, U1, zp);
        gemm_dual<2><<<dim3(32, 2, Bc), b256, 0, stream>>>(U1, WBp + W_TB3_2_T1, 256,
            WBp + W_TB3_2_T0, 4, tb3_b2, U3, U2, zp);
        // --- attention ---
        gemm64<0, 0, 0><<<dim3(64, 3, Bc), b256, 0, stream>>>(U2, WBp + W_ATTN_IN, 256, 768,
            attn_in_b, nullptr, Q, nullptr, nullptr, nullptr, nullptr, nullptr);
        attn_win<<<dim3(16, 4, Bc), b256, 0, stream>>>(Q, U3);
        // attn_out GEMM + residual(x4) + LN1 -> xn
        gemm64<0, 0, 1><<<dim3(64, 1, Bc), b256, 0, stream>>>(U3, WBp + W_ATTN_OUT, 256, 256,
            attn_out_b, U2, U1, ln1_g, ln1_b, nullptr, nullptr, nullptr);
        // --- FFN ---
        gemm64<2, 0, 0><<<dim3(64, 2, Bc), b256, 0, stream>>>(U1, WBp + W_FFN1, 256, 512,
            ffn_b1, nullptr, F, nullptr, nullptr, nullptr, nullptr, nullptr);
        // FFN2 + residual(xn) + LN2 + final projection -> out
        gemm64<0, 0, 2><<<dim3(64, 1, Bc), b256, 0, stream>>>(F, WBp + W_FFN2, 512, 256,
            ffn_b2, U1, nullptr, ln2_g, ln2_b, last_w, last_b, oc);
    }
}